// Round 16
// baseline (218.016 us; speedup 1.0000x reference)
//
#include <hip/hip_runtime.h>
#include <hip/hip_fp16.h>
#include <stdint.h>

typedef unsigned int u32;

#define Bn 8
#define Hn 768
#define Wn 1280
#define HWs (Hn*Wn)          // 983040
#define Rr 40
#define NNinv (1.0f/6561.0f)
#define KTOP 983
#define BETA_C (2.996f/300.0f)
#define EQCAP 4096
#define TK_BPI 480           // top-k blocks per image = HWs/2048
#define NCH 96               // 8-row chunks
#define SEGV 16
#define NSEGV 48             // Hn/SEGV
#define HIMG 4               // images per half-batch (fallback path)
#define TW 640               // output cols per x-tile
#define CW 680               // field cols per x-tile (40 halo, clipped at image edge)
#define NGA (Bn*NCH*2)       // 1536 gA/gB blocks
#define NVF ((Bn*Wn*NSEGV)/256)  // 1920 vAf/vBf blocks

// ---- FULL-batch ws layout (floats) ----
#define OFF_F     0                     // F fp16x4: 16*HWs floats
#define OFF_AB1   (16*HWs)              // a,b fp16x2: 8*HWs floats
#define OFF_AB2   (24*HWs)              // h-summed a,b fp16x2: 8*HWs floats
#define OFF_CS4f  (32*HWs)              // chunk sums of F: 4*HWs floats
#define OFF_CS2f  (36*HWs)              // chunk sums of AB2: 2*HWs floats
#define OFF_TAILf (38*HWs)

// ---- HALF-batch (fallback) ws layout ----
#define OFFH_FOVF 0
#define OFFH_AB   (4*HWs)
#define CS_N      (HIMG*NCH*Wn)
#define OFFH_CS4  (12*HWs)
#define OFFH_CS2  (OFFH_CS4 + 4*CS_N)
#define OFFH_TAIL (OFFH_CS2 + 2*CS_N)

// must-zero tail prefix: hist1 + hist2 + eqCount
#define ZERO_U32  (Bn*4096 + Bn*65536 + Bn)   // 557064
#define ZERO_U4   (ZERO_U32/4 + 1)

__device__ __forceinline__ float4 f4add(float4 a, float4 b){ return make_float4(a.x+b.x,a.y+b.y,a.z+b.z,a.w+b.w); }
__device__ __forceinline__ float4 f4sub(float4 a, float4 b){ return make_float4(a.x-b.x,a.y-b.y,a.z-b.z,a.w-b.w); }

__device__ __forceinline__ u32 h2_to_u32(__half2 h){ union { __half2 h; u32 u; } c; c.h = h; return c.u; }
__device__ __forceinline__ __half2 u32_to_h2(u32 u){ union { u32 u; __half2 h; } c; c.u = u; return c.h; }

// ---------------- fast zero of the top-k accumulators ----------------
__global__ __launch_bounds__(256) void fill0_kernel(uint4* __restrict__ p){
  int i = blockIdx.x*256 + threadIdx.x;
  if (i < ZERO_U4) p[i] = make_uint4(0,0,0,0);
}

// ================= FULL-BATCH PATH (fused dispatches, INTERLEAVED block demux) =================

// gA fused with tk1 — interleaved: grid 1792 = 256 groups x (6 gA + 1 tk1).
// tk1 blocks dispatch early -> co-resident with gA -> latency hidden (round-15's
// tail-scheduled tk1 added ~23 µs).
__global__ __launch_bounds__(256) void gA_tk1_kernel(const float* __restrict__ img, const float* __restrict__ depth,
    uint2* __restrict__ F, float4* __restrict__ CS4, u32* __restrict__ hist1){
  __shared__ union SM {
    u32 lh[4096];                                    // tk1: 2 hists x 2048 packed u16 pairs
    struct { float4 lds[769]; float4 wtot[4]; } g;   // gA (~12.4 KB)
  } sm;
  int tid = threadIdx.x;
  int q = blockIdx.x / 7, r7 = blockIdx.x % 7;
  if (r7 != 6){
    // ---------------- gA (block q*6 + r7) ----------------
    int blk = q*6 + r7;
    int xt = blk & 1;
    int t2 = blk >> 1;
    int b = t2 / NCH, ch = t2 % NCH;
    int x0 = xt*TW;
    int cstart = xt ? (TW - Rr) : 0;
    int lane = tid & 63, wv = tid >> 6;
    float4 acc[3];
    #pragma unroll
    for (int j = 0; j < 3; ++j) acc[j] = make_float4(0,0,0,0);
    const float* irB = img + ((size_t)(b*3+0)*Hn + ch*8)*Wn + cstart;
    const float* igB = img + ((size_t)(b*3+1)*Hn + ch*8)*Wn + cstart;
    const float* ibB = img + ((size_t)(b*3+2)*Hn + ch*8)*Wn + cstart;
    const float* dpB = depth + ((size_t)b*Hn + ch*8)*Wn + cstart;
    float pr[3], pg[3], pb[3], pd[3];
    #pragma unroll
    for (int j = 0; j < 3; ++j){
      int i = tid + j*256;
      if (i < CW){ pr[j]=irB[i]; pg[j]=igB[i]; pb[j]=ibB[i]; pd[j]=dpB[i]; }
    }
    for (int r = 0; r < 8; ++r){
      int y = ch*8 + r;
      __syncthreads();
      #pragma unroll
      for (int j = 0; j < 3; ++j){
        int i = tid + j*256;
        float4 f = make_float4(0,0,0,0);
        if (i < CW){
          float I = 0.299f*pr[j] + 0.587f*pg[j] + 0.114f*pb[j];
          float p = fminf(fmaxf(expf(-BETA_C*pd[j]), 0.0f), 1.0f);
          f = make_float4(I, p, I*p, I*I);
        }
        sm.g.lds[i] = f;
      }
      if (r < 7){
        size_t off = (size_t)(r+1)*Wn;
        #pragma unroll
        for (int j = 0; j < 3; ++j){
          int i = tid + j*256;
          if (i < CW){ pr[j]=irB[off+i]; pg[j]=igB[off+i]; pb[j]=ibB[off+i]; pd[j]=dpB[off+i]; }
        }
      }
      __syncthreads();
      int base = tid*3;
      float4 loc[3]; float4 tsum = make_float4(0,0,0,0);
      #pragma unroll
      for (int j = 0; j < 3; ++j){ loc[j] = sm.g.lds[base+j]; tsum = f4add(tsum, loc[j]); }
      float4 v = tsum;
      for (int d = 1; d < 64; d <<= 1){
        float4 o; o.x = __shfl_up(v.x, d); o.y = __shfl_up(v.y, d); o.z = __shfl_up(v.z, d); o.w = __shfl_up(v.w, d);
        if (lane >= d) v = f4add(v, o);
      }
      if (lane == 63) sm.g.wtot[wv] = v;
      __syncthreads();
      float4 ex = f4sub(v, tsum);
      for (int w = 0; w < wv; ++w) ex = f4add(ex, sm.g.wtot[w]);
      float4 run = ex;
      #pragma unroll
      for (int j = 0; j < 3; ++j){ sm.g.lds[base+j] = run; run = f4add(run, loc[j]); }
      __syncthreads();
      #pragma unroll
      for (int j = 0; j < 3; ++j){
        int lx = tid + j*256;
        if (lx < TW){
          int gx = x0 + lx;
          int hi = gx + Rr + 1; if (hi > Wn) hi = Wn;
          int lo = gx - Rr;     if (lo < 0)  lo = 0;
          float4 s = f4sub(sm.g.lds[hi - cstart], sm.g.lds[lo - cstart]);
          __half2 h01 = __float22half2_rn(make_float2(s.x, s.y));
          __half2 h23 = __float22half2_rn(make_float2(s.z, s.w));
          F[(size_t)b*HWs + (size_t)y*Wn + gx] = make_uint2(h2_to_u32(h01), h2_to_u32(h23));
          float2 f0 = __half22float2(h01), f1 = __half22float2(h23);
          acc[j] = f4add(acc[j], make_float4(f0.x, f0.y, f1.x, f1.y));
        }
      }
    }
    #pragma unroll
    for (int j = 0; j < 3; ++j){
      int lx = tid + j*256;
      if (lx < TW) CS4[((size_t)b*NCH + ch)*Wn + x0 + lx] = acc[j];
    }
  } else {
    // ---------------- tk1 (block q in [0,256); 2 wave-pair histograms) ----------------
    for (int i = tid; i < 4096; i += 256) sm.lh[i] = 0;
    __syncthreads();
    int blk = q;                     // [0, Bn*32)
    int b = blk >> 5;
    int slice = blk & 31;
    const int per = HWs/32;          // 30720 -> 15360 per wave-pair, fits u16 halves
    int start = b*HWs + slice*per;
    u32* h = &sm.lh[(tid >> 7) * 2048];   // waves 0-1 -> hist0, waves 2-3 -> hist1
    const float2* dp = (const float2*)(depth + start);
    for (int i = tid; i < per/2; i += 256){
      float2 v = dp[i];
      u32 u0 = __float_as_uint(v.x), u1 = __float_as_uint(v.y);
      u32 b0 = u0 >> 20, b1 = u1 >> 20;
      atomicAdd(&h[b0 >> 1], (b0 & 1u) ? 65536u : 1u);
      atomicAdd(&h[b1 >> 1], (b1 & 1u) ? 65536u : 1u);
    }
    __syncthreads();
    for (int i = tid; i < 4096; i += 256){
      u32 s = 0;
      for (int w = 0; w < 2; ++w) s += (sm.lh[w*2048 + (i>>1)] >> ((i&1)*16)) & 0xFFFFu;
      if (s) atomicAdd(&hist1[b*4096+i], s);
    }
  }
}

// vAf fused with tk3 — interleaved: grid 5760 = 1920 groups x (1 vAf + 2 tk3)
__global__ __launch_bounds__(256) void vAf_tk3_kernel(const uint2* __restrict__ F, const float4* __restrict__ CS,
    u32* __restrict__ AB, const float* __restrict__ depth, const u32* __restrict__ selP1, u32* __restrict__ hist2){
  int q = blockIdx.x / 3, r3 = blockIdx.x % 3;
  if (r3 == 0){
    // ---------------- vAf (block q) ----------------
    int gt = q*256 + threadIdx.x;
    int x  = gt % Wn;
    int t2 = gt / Wn;
    int b = t2 % Bn, s = t2 / Bn;
    const uint2* Fb   = F + (size_t)b*HWs;
    const float4* CSb = CS + (size_t)b*NCH*Wn;
    int y0 = s*SEGV;
    int c0 = 2*s - 5; if (c0 < 0) c0 = 0;
    int c1 = 2*s + 5; if (c1 > NCH) c1 = NCH;
    float4 S = make_float4(0,0,0,0);
    for (int c = c0; c < c1; ++c) S = f4add(S, CSb[(size_t)c*Wn + x]);
    u32* ABb = AB + (size_t)b*HWs;
    #pragma unroll 8
    for (int y = y0; y < y0 + SEGV; ++y){
      int ya = y + Rr;
      if (ya < Hn){
        uint2 u = Fb[(size_t)ya*Wn + x];
        float2 f0 = __half22float2(u32_to_h2(u.x)), f1 = __half22float2(u32_to_h2(u.y));
        S.x += f0.x; S.y += f0.y; S.z += f1.x; S.w += f1.y;
      }
      float mI = S.x*NNinv, mp = S.y*NNinv, mIp = S.z*NNinv, mII = S.w*NNinv;
      float var = mII - mI*mI;
      float a  = (mIp - mI*mp) / (var + 1e-3f);
      float bb = mp - a*mI;
      ABb[(size_t)y*Wn + x] = h2_to_u32(__float22half2_rn(make_float2(a, bb)));
      int yb = y - Rr;
      if (yb >= 0){
        uint2 u = Fb[(size_t)yb*Wn + x];
        float2 f0 = __half22float2(u32_to_h2(u.x)), f1 = __half22float2(u32_to_h2(u.y));
        S.x -= f0.x; S.y -= f0.y; S.z -= f1.x; S.w -= f1.y;
      }
    }
  } else {
    // ---------------- tk3 (block q*2 + r3-1) ----------------
    int blk = q*2 + (r3 - 1);        // [0, Bn*TK_BPI)
    int idx = blk*2048 + threadIdx.x;
    int b = blk / TK_BPI;
    u32 p1 = selP1[b];
    for (int it = 0; it < 8; ++it, idx += 256){
      u32 u = __float_as_uint(depth[idx]);
      if ((u>>20) == p1) atomicAdd(&hist2[b*65536 + ((u>>4)&0xFFFFu)], 1u);
    }
  }
}

// gB fused with tk5 — interleaved: grid 5376 = 768 groups x (2 gB + 5 tk5)
__global__ __launch_bounds__(256) void gB_tk5_kernel(const u32* __restrict__ AB1, u32* __restrict__ AB2,
    float2* __restrict__ CS2, const float* __restrict__ depth, const float* __restrict__ img,
    const u32* __restrict__ selTau, u32* __restrict__ eqCount, u32* __restrict__ eqVal, u32* __restrict__ eqIdx,
    float* __restrict__ partial){
  __shared__ union SM {
    struct { float2 lds[769]; float2 wtot[4]; } g;
    float wsum[12];
  } sm;
  int tid = threadIdx.x;
  int q = blockIdx.x / 7, r7 = blockIdx.x % 7;
  if (r7 < 2){
    // ---------------- gB (block q*2 + r7) ----------------
    int blk = q*2 + r7;
    int xt = blk & 1;
    int t2 = blk >> 1;
    int b = t2 / NCH, ch = t2 % NCH;
    int x0 = xt*TW;
    int cstart = xt ? (TW - Rr) : 0;
    int lane = tid & 63, wv = tid >> 6;
    float2 acc[3];
    #pragma unroll
    for (int j = 0; j < 3; ++j) acc[j] = make_float2(0,0);
    const u32* rowB = AB1 + (size_t)b*HWs + (size_t)(ch*8)*Wn + cstart;
    u32 pv[3];
    #pragma unroll
    for (int j = 0; j < 3; ++j){
      int i = tid + j*256;
      if (i < CW) pv[j] = rowB[i];
    }
    for (int r = 0; r < 8; ++r){
      int y = ch*8 + r;
      __syncthreads();
      #pragma unroll
      for (int j = 0; j < 3; ++j){
        int i = tid + j*256;
        float2 f = make_float2(0,0);
        if (i < CW) f = __half22float2(u32_to_h2(pv[j]));
        sm.g.lds[i] = f;
      }
      if (r < 7){
        size_t off = (size_t)(r+1)*Wn;
        #pragma unroll
        for (int j = 0; j < 3; ++j){
          int i = tid + j*256;
          if (i < CW) pv[j] = rowB[off+i];
        }
      }
      __syncthreads();
      int base = tid*3;
      float2 loc[3]; float2 tsum = make_float2(0,0);
      #pragma unroll
      for (int j = 0; j < 3; ++j){ loc[j] = sm.g.lds[base+j]; tsum.x += loc[j].x; tsum.y += loc[j].y; }
      float2 v = tsum;
      for (int d = 1; d < 64; d <<= 1){
        float2 o; o.x = __shfl_up(v.x, d); o.y = __shfl_up(v.y, d);
        if (lane >= d){ v.x += o.x; v.y += o.y; }
      }
      if (lane == 63) sm.g.wtot[wv] = v;
      __syncthreads();
      float2 ex = make_float2(v.x - tsum.x, v.y - tsum.y);
      for (int w = 0; w < wv; ++w){ ex.x += sm.g.wtot[w].x; ex.y += sm.g.wtot[w].y; }
      float2 run = ex;
      #pragma unroll
      for (int j = 0; j < 3; ++j){ sm.g.lds[base+j] = run; run.x += loc[j].x; run.y += loc[j].y; }
      __syncthreads();
      #pragma unroll
      for (int j = 0; j < 3; ++j){
        int lx = tid + j*256;
        if (lx < TW){
          int gx = x0 + lx;
          int hi = gx + Rr + 1; if (hi > Wn) hi = Wn;
          int lo = gx - Rr;     if (lo < 0)  lo = 0;
          float2 s = make_float2(sm.g.lds[hi - cstart].x - sm.g.lds[lo - cstart].x,
                                 sm.g.lds[hi - cstart].y - sm.g.lds[lo - cstart].y);
          __half2 h = __float22half2_rn(s);
          AB2[(size_t)b*HWs + (size_t)y*Wn + gx] = h2_to_u32(h);
          float2 fr = __half22float2(h);
          acc[j].x += fr.x; acc[j].y += fr.y;
        }
      }
    }
    #pragma unroll
    for (int j = 0; j < 3; ++j){
      int lx = tid + j*256;
      if (lx < TW) CS2[((size_t)b*NCH + ch)*Wn + x0 + lx] = acc[j];
    }
  } else {
    // ---------------- tk5 (block q*5 + r7-2) ----------------
    int blk = q*5 + (r7 - 2);        // [0, Bn*TK_BPI)
    int b = blk / TK_BPI;
    u32 tau = selTau[b];
    int idx = blk*2048 + tid;
    float cr = 0.f, cg = 0.f, cb = 0.f;
    for (int it = 0; it < 8; ++it, idx += 256){
      int pix = idx - b*HWs;
      u32 u = __float_as_uint(depth[idx]);
      u32 u28 = u >> 4;
      if (u28 > tau){
        cr += img[(size_t)(b*3+0)*HWs + pix];
        cg += img[(size_t)(b*3+1)*HWs + pix];
        cb += img[(size_t)(b*3+2)*HWs + pix];
      } else if (u28 == tau){
        u32 p = atomicAdd(&eqCount[b], 1u);
        if (p < EQCAP){ eqVal[b*EQCAP+p] = u; eqIdx[b*EQCAP+p] = (u32)pix; }
      }
    }
    for (int d = 32; d; d >>= 1){
      cr += __shfl_down(cr, d); cg += __shfl_down(cg, d); cb += __shfl_down(cb, d);
    }
    int lane = tid & 63, wv = tid >> 6;
    if (lane == 0){ sm.wsum[wv*3+0] = cr; sm.wsum[wv*3+1] = cg; sm.wsum[wv*3+2] = cb; }
    __syncthreads();
    if (tid == 0){
      float r = 0.f, g = 0.f, bl = 0.f;
      for (int w = 0; w < 4; ++w){ r += sm.wsum[w*3+0]; g += sm.wsum[w*3+1]; bl += sm.wsum[w*3+2]; }
      partial[blk*3+0] = r; partial[blk*3+1] = g; partial[blk*3+2] = bl;
    }
  }
}

// vB: vertical sliding box on (a,b) + fused blend -> out
__global__ __launch_bounds__(256) void vBf_kernel(const u32* __restrict__ AB2, const float2* __restrict__ CS,
    const float* __restrict__ img, const float* __restrict__ Avec, float* __restrict__ out){
  int gt = blockIdx.x*256 + threadIdx.x;
  int x  = gt % Wn;
  int t2 = gt / Wn;
  int b = t2 % Bn, s = t2 / Bn;
  const u32* ABb = AB2 + (size_t)b*HWs;
  const float2* CSb = CS + (size_t)b*NCH*Wn;
  int y0 = s*SEGV;
  int c0 = 2*s - 5; if (c0 < 0) c0 = 0;
  int c1 = 2*s + 5; if (c1 > NCH) c1 = NCH;
  float2 S = make_float2(0,0);
  for (int c = c0; c < c1; ++c){ float2 t = CSb[(size_t)c*Wn + x]; S.x += t.x; S.y += t.y; }
  float A0 = Avec[b*3+0], A1 = Avec[b*3+1], A2 = Avec[b*3+2];
  const float* ir = img + (size_t)(b*3+0)*HWs;
  const float* ig = img + (size_t)(b*3+1)*HWs;
  const float* ib = img + (size_t)(b*3+2)*HWs;
  float* o0 = out + (size_t)(b*3+0)*HWs;
  float* o1 = out + (size_t)(b*3+1)*HWs;
  float* o2 = out + (size_t)(b*3+2)*HWs;
  #pragma unroll 8
  for (int y = y0; y < y0 + SEGV; ++y){
    int ya = y + Rr;
    if (ya < Hn){ float2 t = __half22float2(u32_to_h2(ABb[(size_t)ya*Wn + x])); S.x += t.x; S.y += t.y; }
    float ma = S.x*NNinv, mb = S.y*NNinv;
    size_t idx = (size_t)y*Wn + x;
    float r = ir[idx], g = ig[idx], bb = ib[idx];
    float gray = 0.299f*r + 0.587f*g + 0.114f*bb;
    float t = ma*gray + mb;
    o0[idx] = r *t + A0*(1.0f - t);
    o1[idx] = g *t + A1*(1.0f - t);
    o2[idx] = bb*t + A2*(1.0f - t);
    int yb = y - Rr;
    if (yb >= 0){ float2 t2v = __half22float2(u32_to_h2(ABb[(size_t)yb*Wn + x])); S.x -= t2v.x; S.y -= t2v.y; }
  }
}

// ================= small top-k kernels (shared by both paths) =================

__global__ __launch_bounds__(256) void tk2_kernel(const u32* __restrict__ hist1,
    u32* __restrict__ selP1, u32* __restrict__ selK1){
  int b = blockIdx.x, tid = threadIdx.x;
  const u32* h = hist1 + b*4096;
  u32 cs = 0; int bb = tid*16;
  for (int i = 0; i < 16; ++i) cs += h[bb+i];
  __shared__ u32 sums[256];
  sums[tid] = cs; __syncthreads();
  u32 above = 0;
  for (int t = tid+1; t < 256; ++t) above += sums[t];
  if (above < KTOP && above + cs >= KTOP){
    u32 acc = above;
    for (int i = 15; i >= 0; --i){
      u32 c = h[bb+i]; acc += c;
      if (acc >= KTOP){ selP1[b] = (u32)(bb+i); selK1[b] = KTOP - (acc - c); break; }
    }
  }
}

__global__ __launch_bounds__(256) void tk4_kernel(const u32* __restrict__ hist2, const u32* __restrict__ selP1,
    const u32* __restrict__ selK1, u32* __restrict__ selTau, u32* __restrict__ selK2){
  int b = blockIdx.x, tid = threadIdx.x;
  const u32* h = hist2 + b*65536;
  u32 kk = selK1[b];
  u32 cs = 0; int bb = tid*256;
  for (int i = 0; i < 256; ++i) cs += h[bb+i];
  __shared__ u32 sums[256];
  sums[tid] = cs; __syncthreads();
  u32 above = 0;
  for (int t = tid+1; t < 256; ++t) above += sums[t];
  if (above < kk && above + cs >= kk){
    u32 acc = above;
    for (int i = 255; i >= 0; --i){
      u32 c = h[bb+i]; acc += c;
      if (acc >= kk){ selTau[b] = (selP1[b]<<16) | (u32)(bb+i); selK2[b] = kk - (acc - c); break; }
    }
  }
}

__global__ void tk6_kernel(const float* __restrict__ img, const u32* __restrict__ eqCount,
    u32* __restrict__ eqVal, const u32* __restrict__ eqIdx, const u32* __restrict__ selK2,
    const float* __restrict__ partial, float* __restrict__ Avec){
  int b = blockIdx.x;
  int tid = threadIdx.x;
  float r = 0.f, g = 0.f, bl = 0.f;
  for (int i = tid; i < TK_BPI; i += 64){
    r  += partial[(b*TK_BPI+i)*3+0];
    g  += partial[(b*TK_BPI+i)*3+1];
    bl += partial[(b*TK_BPI+i)*3+2];
  }
  for (int d = 32; d; d >>= 1){
    r += __shfl_down(r, d); g += __shfl_down(g, d); bl += __shfl_down(bl, d);
  }
  if (tid != 0) return;
  u32 m = eqCount[b]; if (m > EQCAP) m = EQCAP;
  u32 need = selK2[b]; if (need > m) need = m;
  float cr = r, cg = g, cb = bl;
  for (u32 it = 0; it < need; ++it){
    int best = -1; u32 bv = 0, bi = 0;
    for (u32 j = 0; j < m; ++j){
      u32 vv = eqVal[b*EQCAP+j];
      if (vv == 0xFFFFFFFFu) continue;
      u32 ix = eqIdx[b*EQCAP+j];
      if (best < 0 || vv > bv || (vv == bv && ix < bi)){ best = (int)j; bv = vv; bi = ix; }
    }
    eqVal[b*EQCAP+best] = 0xFFFFFFFFu;
    cr += img[(size_t)(b*3+0)*HWs + bi];
    cg += img[(size_t)(b*3+1)*HWs + bi];
    cb += img[(size_t)(b*3+2)*HWs + bi];
  }
  float inv = 1.0f/(float)KTOP;
  Avec[b*3+0] = cr*inv; Avec[b*3+1] = cg*inv; Avec[b*3+2] = cb*inv;
}

// ================= FALLBACK (two-half fp32) PATH + standalone tk1/tk3/tk5 =================

__global__ __launch_bounds__(1024) void tk1_kernel(const float* __restrict__ depth, u32* __restrict__ hist1){
  __shared__ u32 lh[16*2048];
  int tid = threadIdx.x;
  for (int i = tid; i < 16*2048; i += 1024) lh[i] = 0;
  __syncthreads();
  int b = blockIdx.x >> 5;
  int slice = blockIdx.x & 31;
  const int per = HWs/32;
  int start = b*HWs + slice*per;
  u32* h = &lh[(tid >> 6) * 2048];
  const float2* dp = (const float2*)(depth + start);
  for (int i = tid; i < per/2; i += 1024){
    float2 v = dp[i];
    u32 u0 = __float_as_uint(v.x), u1 = __float_as_uint(v.y);
    u32 b0 = u0 >> 20, b1 = u1 >> 20;
    atomicAdd(&h[b0 >> 1], (b0 & 1u) ? 65536u : 1u);
    atomicAdd(&h[b1 >> 1], (b1 & 1u) ? 65536u : 1u);
  }
  __syncthreads();
  for (int i = tid; i < 4096; i += 1024){
    u32 s = 0;
    for (int w = 0; w < 16; ++w) s += (lh[w*2048 + (i>>1)] >> ((i&1)*16)) & 0xFFFFu;
    if (s) atomicAdd(&hist1[b*4096+i], s);
  }
}

__global__ __launch_bounds__(256) void tk3_kernel(const float* __restrict__ depth,
    const u32* __restrict__ selP1, u32* __restrict__ hist2){
  int idx = blockIdx.x*2048 + threadIdx.x;
  int b = blockIdx.x / TK_BPI;
  u32 p1 = selP1[b];
  for (int it = 0; it < 8; ++it, idx += 256){
    u32 u = __float_as_uint(depth[idx]);
    if ((u>>20) == p1) atomicAdd(&hist2[b*65536 + ((u>>4)&0xFFFFu)], 1u);
  }
}

__global__ __launch_bounds__(256) void tk5_kernel(const float* __restrict__ depth, const float* __restrict__ img,
    const u32* __restrict__ selTau, u32* __restrict__ eqCount, u32* __restrict__ eqVal, u32* __restrict__ eqIdx,
    float* __restrict__ partial){
  int blk = blockIdx.x;
  int b = blk / TK_BPI;
  u32 tau = selTau[b];
  int idx = blk*2048 + threadIdx.x;
  float cr = 0.f, cg = 0.f, cb = 0.f;
  for (int it = 0; it < 8; ++it, idx += 256){
    int pix = idx - b*HWs;
    u32 u = __float_as_uint(depth[idx]);
    u32 u28 = u >> 4;
    if (u28 > tau){
      cr += img[(size_t)(b*3+0)*HWs + pix];
      cg += img[(size_t)(b*3+1)*HWs + pix];
      cb += img[(size_t)(b*3+2)*HWs + pix];
    } else if (u28 == tau){
      u32 p = atomicAdd(&eqCount[b], 1u);
      if (p < EQCAP){ eqVal[b*EQCAP+p] = u; eqIdx[b*EQCAP+p] = (u32)pix; }
    }
  }
  for (int d = 32; d; d >>= 1){
    cr += __shfl_down(cr, d); cg += __shfl_down(cg, d); cb += __shfl_down(cb, d);
  }
  __shared__ float wsum[4][3];
  int lane = threadIdx.x & 63, wv = threadIdx.x >> 6;
  if (lane == 0){ wsum[wv][0] = cr; wsum[wv][1] = cg; wsum[wv][2] = cb; }
  __syncthreads();
  if (threadIdx.x == 0){
    float r = 0.f, g = 0.f, bl = 0.f;
    for (int w = 0; w < 4; ++w){ r += wsum[w][0]; g += wsum[w][1]; bl += wsum[w][2]; }
    partial[blk*3+0] = r; partial[blk*3+1] = g; partial[blk*3+2] = bl;
  }
}

__global__ __launch_bounds__(256) void hA_kernel(const float* __restrict__ img, const float* __restrict__ depth,
    float4* __restrict__ Fd, float4* __restrict__ Fw, int half){
  __shared__ float4 lds[Wn+1];
  __shared__ float4 wtot[4];
  int blk = blockIdx.x;
  int bl = blk / Hn, y = blk % Hn;
  int b = half*HIMG + bl;
  const float* ir = img + ((size_t)(b*3+0)*Hn + y)*Wn;
  const float* ig = img + ((size_t)(b*3+1)*Hn + y)*Wn;
  const float* ib = img + ((size_t)(b*3+2)*Hn + y)*Wn;
  const float* dp = depth + ((size_t)b*Hn + y)*Wn;
  int tid = threadIdx.x;
  for (int i = tid; i < Wn; i += 256){
    float r = ir[i], g = ig[i], bb = ib[i];
    float I = 0.299f*r + 0.587f*g + 0.114f*bb;
    float p = expf(-BETA_C*dp[i]);
    p = fminf(fmaxf(p, 0.0f), 1.0f);
    lds[i] = make_float4(I, p, I*p, I*I);
  }
  __syncthreads();
  float4 loc[5]; float4 tsum = make_float4(0,0,0,0);
  for (int j = 0; j < 5; ++j){ loc[j] = lds[tid*5+j]; tsum = f4add(tsum, loc[j]); }
  int lane = tid & 63, wv = tid >> 6;
  float4 v = tsum;
  for (int d = 1; d < 64; d <<= 1){
    float4 o; o.x = __shfl_up(v.x, d); o.y = __shfl_up(v.y, d); o.z = __shfl_up(v.z, d); o.w = __shfl_up(v.w, d);
    if (lane >= d) v = f4add(v, o);
  }
  if (lane == 63) wtot[wv] = v;
  __syncthreads();
  float4 ex = f4sub(v, tsum);
  for (int w = 0; w < wv; ++w) ex = f4add(ex, wtot[w]);
  float4 run = ex;
  for (int j = 0; j < 5; ++j){ lds[tid*5+j] = run; run = f4add(run, loc[j]); }
  if (tid == 255) lds[Wn] = run;
  __syncthreads();
  float4* F = (bl < 3) ? (Fd + (size_t)bl*HWs) : Fw;
  for (int j = 0; j < 5; ++j){
    int xx = tid + j*256;
    int hi = xx + Rr + 1; if (hi > Wn) hi = Wn;
    int lo = xx - Rr;     if (lo < 0)  lo = 0;
    F[(size_t)y*Wn + xx] = f4sub(lds[hi], lds[lo]);
  }
}

__global__ __launch_bounds__(256) void cs4_kernel(const float4* __restrict__ Fd, const float4* __restrict__ Fw,
    float4* __restrict__ CS){
  int gt = blockIdx.x*256 + threadIdx.x;
  int x  = gt % Wn;
  int t2 = gt / Wn;
  int bl = t2 % HIMG, ch = t2 / HIMG;
  const float4* F = (bl < 3) ? (Fd + (size_t)bl*HWs) : Fw;
  const float4* p = F + (size_t)ch*8*Wn + x;
  float4 s = make_float4(0,0,0,0);
  #pragma unroll
  for (int i = 0; i < 8; ++i) s = f4add(s, p[(size_t)i*Wn]);
  CS[((size_t)bl*NCH + ch)*Wn + x] = s;
}

__global__ __launch_bounds__(256) void vA_kernel(const float4* __restrict__ Fd, const float4* __restrict__ Fw,
    const float4* __restrict__ CS, float2* __restrict__ AB){
  int gt = blockIdx.x*256 + threadIdx.x;
  int x  = gt % Wn;
  int t2 = gt / Wn;
  int bl = t2 % HIMG, s = t2 / HIMG;
  const float4* F   = (bl < 3) ? (Fd + (size_t)bl*HWs) : Fw;
  const float4* CSb = CS + (size_t)bl*NCH*Wn;
  int y0 = s*SEGV;
  int c0 = 2*s - 5; if (c0 < 0) c0 = 0;
  int c1 = 2*s + 5; if (c1 > NCH) c1 = NCH;
  float4 S = make_float4(0,0,0,0);
  for (int c = c0; c < c1; ++c) S = f4add(S, CSb[(size_t)c*Wn + x]);
  float2* ABb = AB + (size_t)bl*HWs;
  #pragma unroll 2
  for (int y = y0; y < y0 + SEGV; ++y){
    int ya = y + Rr;
    if (ya < Hn) S = f4add(S, F[(size_t)ya*Wn + x]);
    float mI = S.x*NNinv, mp = S.y*NNinv, mIp = S.z*NNinv, mII = S.w*NNinv;
    float var = mII - mI*mI;
    float a  = (mIp - mI*mp) / (var + 1e-3f);
    float bb = mp - a*mI;
    ABb[(size_t)y*Wn + x] = make_float2(a, bb);
    int yb = y - Rr;
    if (yb >= 0) S = f4sub(S, F[(size_t)yb*Wn + x]);
  }
}

__global__ __launch_bounds__(256) void hB_kernel(float2* __restrict__ AB){
  __shared__ float2 lds[Wn+1];
  __shared__ float2 wtot[4];
  int blk = blockIdx.x;
  int bl = blk / Hn, y = blk % Hn;
  float2* row = AB + ((size_t)bl*Hn + y)*Wn;
  int tid = threadIdx.x;
  for (int i = tid; i < Wn; i += 256) lds[i] = row[i];
  __syncthreads();
  float2 loc[5]; float2 tsum = make_float2(0,0);
  for (int j = 0; j < 5; ++j){ loc[j] = lds[tid*5+j]; tsum.x += loc[j].x; tsum.y += loc[j].y; }
  int lane = tid & 63, wv = tid >> 6;
  float2 v = tsum;
  for (int d = 1; d < 64; d <<= 1){
    float2 o; o.x = __shfl_up(v.x, d); o.y = __shfl_up(v.y, d);
    if (lane >= d){ v.x += o.x; v.y += o.y; }
  }
  if (lane == 63) wtot[wv] = v;
  __syncthreads();
  float2 ex = make_float2(v.x - tsum.x, v.y - tsum.y);
  for (int w = 0; w < wv; ++w){ ex.x += wtot[w].x; ex.y += wtot[w].y; }
  float2 run = ex;
  for (int j = 0; j < 5; ++j){ lds[tid*5+j] = run; run.x += loc[j].x; run.y += loc[j].y; }
  if (tid == 255) lds[Wn] = run;
  __syncthreads();
  for (int j = 0; j < 5; ++j){
    int xx = tid + j*256;
    int hi = xx + Rr + 1; if (hi > Wn) hi = Wn;
    int lo = xx - Rr;     if (lo < 0)  lo = 0;
    row[xx] = make_float2(lds[hi].x - lds[lo].x, lds[hi].y - lds[lo].y);
  }
}

__global__ __launch_bounds__(256) void cs2_kernel(const float2* __restrict__ AB, float2* __restrict__ CS){
  int gt = blockIdx.x*256 + threadIdx.x;
  int x  = gt % Wn;
  int t2 = gt / Wn;
  int bl = t2 % HIMG, ch = t2 / HIMG;
  const float2* p = AB + (size_t)bl*HWs + (size_t)ch*8*Wn + x;
  float2 s = make_float2(0,0);
  #pragma unroll
  for (int i = 0; i < 8; ++i){ s.x += p[(size_t)i*Wn].x; s.y += p[(size_t)i*Wn].y; }
  CS[((size_t)bl*NCH + ch)*Wn + x] = s;
}

__global__ __launch_bounds__(256) void vB_kernel(const float2* __restrict__ AB, const float2* __restrict__ CS,
    const float* __restrict__ img, const float* __restrict__ Avec, float* __restrict__ out, int half){
  int gt = blockIdx.x*256 + threadIdx.x;
  int x  = gt % Wn;
  int t2 = gt / Wn;
  int bl = t2 % HIMG, s = t2 / HIMG;
  int b = half*HIMG + bl;
  const float2* ABb = AB + (size_t)bl*HWs;
  const float2* CSb = CS + (size_t)bl*NCH*Wn;
  int y0 = s*SEGV;
  int c0 = 2*s - 5; if (c0 < 0) c0 = 0;
  int c1 = 2*s + 5; if (c1 > NCH) c1 = NCH;
  float2 S = make_float2(0,0);
  for (int c = c0; c < c1; ++c){ float2 t = CSb[(size_t)c*Wn + x]; S.x += t.x; S.y += t.y; }
  float A0 = Avec[b*3+0], A1 = Avec[b*3+1], A2 = Avec[b*3+2];
  const float* ir = img + (size_t)(b*3+0)*HWs;
  const float* ig = img + (size_t)(b*3+1)*HWs;
  const float* ib = img + (size_t)(b*3+2)*HWs;
  float* o0 = out + (size_t)(b*3+0)*HWs;
  float* o1 = out + (size_t)(b*3+1)*HWs;
  float* o2 = out + (size_t)(b*3+2)*HWs;
  #pragma unroll 2
  for (int y = y0; y < y0 + SEGV; ++y){
    int ya = y + Rr;
    if (ya < Hn){ float2 t = ABb[(size_t)ya*Wn + x]; S.x += t.x; S.y += t.y; }
    float ma = S.x*NNinv, mb = S.y*NNinv;
    size_t idx = (size_t)y*Wn + x;
    float r = ir[idx], g = ig[idx], bb = ib[idx];
    float gray = 0.299f*r + 0.587f*g + 0.114f*bb;
    float t = ma*gray + mb;
    o0[idx] = r *t + A0*(1.0f - t);
    o1[idx] = g *t + A1*(1.0f - t);
    o2[idx] = bb*t + A2*(1.0f - t);
    int yb = y - Rr;
    if (yb >= 0){ float2 t2v = ABb[(size_t)yb*Wn + x]; S.x -= t2v.x; S.y -= t2v.y; }
  }
}

// ================= launch =================

extern "C" void kernel_launch(void* const* d_in, const int* in_sizes, int n_in,
                              void* d_out, int out_size, void* d_ws, size_t ws_size,
                              hipStream_t stream){
  const float* img   = (const float*)d_in[0];
  const float* depth = (const float*)d_in[1];
  float* out = (float*)d_out;
  float* ws  = (float*)d_ws;

  const size_t tailFloats = (size_t)ZERO_U32 + 4*Bn + 2*(size_t)Bn*EQCAP
                          + (size_t)Bn*TK_BPI*3 + Bn*3 + 16;
  const size_t needFull = ((size_t)38*HWs + tailFloats) * sizeof(float);
  bool full = (ws_size >= needFull);

  size_t offTail = full ? (size_t)OFF_TAILf : (size_t)OFFH_TAIL;
  u32* tail    = (u32*)(ws + offTail);
  u32* hist1   = tail;                           // Bn*4096
  u32* hist2   = hist1 + Bn*4096;                // Bn*65536
  u32* eqCount = hist2 + (size_t)Bn*65536;       // Bn   (end of zero region)
  u32* selP1   = eqCount + Bn;
  u32* selK1   = selP1 + Bn;
  u32* selTau  = selK1 + Bn;
  u32* selK2   = selTau + Bn;
  u32* eqVal   = selK2 + Bn;                     // Bn*EQCAP
  u32* eqIdx   = eqVal + (size_t)Bn*EQCAP;       // Bn*EQCAP
  float* partial = (float*)(eqIdx + (size_t)Bn*EQCAP);   // Bn*TK_BPI*3
  float* Avec    = partial + (size_t)Bn*TK_BPI*3;        // Bn*3

  fill0_kernel<<<dim3((ZERO_U4 + 255)/256), dim3(256), 0, stream>>>((uint4*)tail);

  if (full){
    uint2*  F   = (uint2*)(ws + OFF_F);
    u32*    AB1 = (u32*)(ws + OFF_AB1);
    u32*    AB2 = (u32*)(ws + OFF_AB2);
    float4* CS4 = (float4*)(ws + OFF_CS4f);
    float2* CS2 = (float2*)(ws + OFF_CS2f);
    gA_tk1_kernel<<<dim3(256*7),            dim3(256), 0, stream>>>(img, depth, F, CS4, hist1);
    tk2_kernel   <<<dim3(Bn),               dim3(256), 0, stream>>>(hist1, selP1, selK1);
    vAf_tk3_kernel<<<dim3(NVF*3),           dim3(256), 0, stream>>>(F, CS4, AB1, depth, selP1, hist2);
    tk4_kernel   <<<dim3(Bn),               dim3(256), 0, stream>>>(hist2, selP1, selK1, selTau, selK2);
    gB_tk5_kernel<<<dim3(768*7),            dim3(256), 0, stream>>>(AB1, AB2, CS2, depth, img, selTau,
                                                                    eqCount, eqVal, eqIdx, partial);
    tk6_kernel   <<<dim3(Bn),               dim3(64),  0, stream>>>(img, eqCount, eqVal, eqIdx, selK2, partial, Avec);
    vBf_kernel   <<<dim3(NVF),              dim3(256), 0, stream>>>(AB2, CS2, img, Avec, out);
  } else {
    // fallback: unfused proven chain
    tk1_kernel<<<dim3(Bn*32), dim3(1024), 0, stream>>>(depth, hist1);
    tk2_kernel<<<dim3(Bn),    dim3(256), 0, stream>>>(hist1, selP1, selK1);
    tk3_kernel<<<dim3(Bn*TK_BPI), dim3(256), 0, stream>>>(depth, selP1, hist2);
    tk4_kernel<<<dim3(Bn),    dim3(256), 0, stream>>>(hist2, selP1, selK1, selTau, selK2);
    tk5_kernel<<<dim3(Bn*TK_BPI), dim3(256), 0, stream>>>(depth, img, selTau, eqCount, eqVal, eqIdx, partial);
    tk6_kernel<<<dim3(Bn),    dim3(64),  0, stream>>>(img, eqCount, eqVal, eqIdx, selK2, partial, Avec);
    float4* Fw  = (float4*)(ws + OFFH_FOVF);
    float2* AB  = (float2*)(ws + OFFH_AB);
    float4* CS4 = (float4*)(ws + OFFH_CS4);
    float2* CS2 = (float2*)(ws + OFFH_CS2);
    for (int half = 0; half < 2; ++half){
      float4* Fd = (float4*)out + (size_t)half*3*HWs;
      hA_kernel <<<dim3(HIMG*Hn),            dim3(256), 0, stream>>>(img, depth, Fd, Fw, half);
      cs4_kernel<<<dim3((HIMG*NCH*Wn)/256),  dim3(256), 0, stream>>>(Fd, Fw, CS4);
      vA_kernel <<<dim3((HIMG*Wn*NSEGV)/256),dim3(256), 0, stream>>>(Fd, Fw, CS4, AB);
      hB_kernel <<<dim3(HIMG*Hn),            dim3(256), 0, stream>>>(AB);
      cs2_kernel<<<dim3((HIMG*NCH*Wn)/256),  dim3(256), 0, stream>>>(AB, CS2);
      vB_kernel <<<dim3((HIMG*Wn*NSEGV)/256),dim3(256), 0, stream>>>(AB, CS2, img, Avec, out, half);
    }
  }
}

// Round 17
// 205.328 us; speedup vs baseline: 1.0618x; 1.0618x over previous
//
#include <hip/hip_runtime.h>
#include <hip/hip_fp16.h>
#include <stdint.h>

typedef unsigned int u32;

#define Bn 8
#define Hn 768
#define Wn 1280
#define HWs (Hn*Wn)          // 983040
#define Rr 40
#define NNinv (1.0f/6561.0f)
#define KTOP 983
#define BETA_C (2.996f/300.0f)
#define EQCAP 4096
#define TK_BPI 480           // top-k blocks per image = HWs/2048
#define NCH 96               // 8-row chunks
#define SEGV 16
#define NSEGV 48             // Hn/SEGV
#define HIMG 4               // images per half-batch (fallback path)
#define TK1_WAVES 16
#define TW 640               // output cols per x-tile
#define CW 680               // field cols per x-tile (40 halo, clipped at image edge)
#define NGA (Bn*NCH*2)       // 1536 gA/gB blocks
#define NVF ((Bn*Wn*NSEGV)/256)  // 1920 vAf/vBf blocks

// ---- FULL-batch ws layout (floats) ----
#define OFF_F     0                     // F fp16x4: 16*HWs floats
#define OFF_AB1   (16*HWs)              // a,b fp16x2: 8*HWs floats
#define OFF_AB2   (24*HWs)              // h-summed a,b fp16x2: 8*HWs floats
#define OFF_CS4f  (32*HWs)              // chunk sums of F: 4*HWs floats
#define OFF_CS2f  (36*HWs)              // chunk sums of AB2: 2*HWs floats
#define OFF_TAILf (38*HWs)

// ---- HALF-batch (fallback) ws layout ----
#define OFFH_FOVF 0
#define OFFH_AB   (4*HWs)
#define CS_N      (HIMG*NCH*Wn)
#define OFFH_CS4  (12*HWs)
#define OFFH_CS2  (OFFH_CS4 + 4*CS_N)
#define OFFH_TAIL (OFFH_CS2 + 2*CS_N)

// must-zero tail prefix: hist1 + hist2 + eqCount
#define ZERO_U32  (Bn*4096 + Bn*65536 + Bn)   // 557064
#define ZERO_U4   (ZERO_U32/4 + 1)

__device__ __forceinline__ float4 f4add(float4 a, float4 b){ return make_float4(a.x+b.x,a.y+b.y,a.z+b.z,a.w+b.w); }
__device__ __forceinline__ float4 f4sub(float4 a, float4 b){ return make_float4(a.x-b.x,a.y-b.y,a.z-b.z,a.w-b.w); }

__device__ __forceinline__ u32 h2_to_u32(__half2 h){ union { __half2 h; u32 u; } c; c.h = h; return c.u; }
__device__ __forceinline__ __half2 u32_to_h2(u32 u){ union { u32 u; __half2 h; } c; c.u = u; return c.h; }

// ---------------- fast zero of the top-k accumulators ----------------
__global__ __launch_bounds__(256) void fill0_kernel(uint4* __restrict__ p){
  int i = blockIdx.x*256 + threadIdx.x;
  if (i < ZERO_U4) p[i] = make_uint4(0,0,0,0);
}

// ================= FULL-BATCH PATH =================

// gA standalone (proven round-12 form: x-split, 8-row chunks, single LDS buffer, register prefetch)
__global__ __launch_bounds__(256) void gA_kernel(const float* __restrict__ img, const float* __restrict__ depth,
    uint2* __restrict__ F, float4* __restrict__ CS4){
  __shared__ float4 lds[769];
  __shared__ float4 wtot[4];
  int blk = blockIdx.x;               // [0, NGA)
  int xt = blk & 1;
  int t2 = blk >> 1;
  int b = t2 / NCH, ch = t2 % NCH;
  int x0 = xt*TW;
  int cstart = xt ? (TW - Rr) : 0;    // 600 or 0
  int tid = threadIdx.x;
  int lane = tid & 63, wv = tid >> 6;
  float4 acc[3];
  #pragma unroll
  for (int j = 0; j < 3; ++j) acc[j] = make_float4(0,0,0,0);
  const float* irB = img + ((size_t)(b*3+0)*Hn + ch*8)*Wn + cstart;
  const float* igB = img + ((size_t)(b*3+1)*Hn + ch*8)*Wn + cstart;
  const float* ibB = img + ((size_t)(b*3+2)*Hn + ch*8)*Wn + cstart;
  const float* dpB = depth + ((size_t)b*Hn + ch*8)*Wn + cstart;
  float pr[3], pg[3], pb[3], pd[3];
  #pragma unroll
  for (int j = 0; j < 3; ++j){
    int i = tid + j*256;
    if (i < CW){ pr[j]=irB[i]; pg[j]=igB[i]; pb[j]=ibB[i]; pd[j]=dpB[i]; }
  }
  for (int r = 0; r < 8; ++r){
    int y = ch*8 + r;
    __syncthreads();   // protect lds from previous iteration's window reads
    #pragma unroll
    for (int j = 0; j < 3; ++j){
      int i = tid + j*256;
      float4 f = make_float4(0,0,0,0);
      if (i < CW){
        float I = 0.299f*pr[j] + 0.587f*pg[j] + 0.114f*pb[j];
        float p = fminf(fmaxf(expf(-BETA_C*pd[j]), 0.0f), 1.0f);
        f = make_float4(I, p, I*p, I*I);
      }
      lds[i] = f;
    }
    if (r < 7){
      size_t off = (size_t)(r+1)*Wn;
      #pragma unroll
      for (int j = 0; j < 3; ++j){
        int i = tid + j*256;
        if (i < CW){ pr[j]=irB[off+i]; pg[j]=igB[off+i]; pb[j]=ibB[off+i]; pd[j]=dpB[off+i]; }
      }
    }
    __syncthreads();   // fields visible
    int base = tid*3;
    float4 loc[3]; float4 tsum = make_float4(0,0,0,0);
    #pragma unroll
    for (int j = 0; j < 3; ++j){ loc[j] = lds[base+j]; tsum = f4add(tsum, loc[j]); }
    float4 v = tsum;
    for (int d = 1; d < 64; d <<= 1){
      float4 o; o.x = __shfl_up(v.x, d); o.y = __shfl_up(v.y, d); o.z = __shfl_up(v.z, d); o.w = __shfl_up(v.w, d);
      if (lane >= d) v = f4add(v, o);
    }
    if (lane == 63) wtot[wv] = v;
    __syncthreads();   // wtot visible; all lds field reads done
    float4 ex = f4sub(v, tsum);
    for (int w = 0; w < wv; ++w) ex = f4add(ex, wtot[w]);
    float4 run = ex;
    #pragma unroll
    for (int j = 0; j < 3; ++j){ lds[base+j] = run; run = f4add(run, loc[j]); }
    __syncthreads();   // prefix visible
    #pragma unroll
    for (int j = 0; j < 3; ++j){
      int lx = tid + j*256;
      if (lx < TW){
        int gx = x0 + lx;
        int hi = gx + Rr + 1; if (hi > Wn) hi = Wn;
        int lo = gx - Rr;     if (lo < 0)  lo = 0;
        float4 s = f4sub(lds[hi - cstart], lds[lo - cstart]);
        __half2 h01 = __float22half2_rn(make_float2(s.x, s.y));
        __half2 h23 = __float22half2_rn(make_float2(s.z, s.w));
        F[(size_t)b*HWs + (size_t)y*Wn + gx] = make_uint2(h2_to_u32(h01), h2_to_u32(h23));
        float2 f0 = __half22float2(h01), f1 = __half22float2(h23);
        acc[j] = f4add(acc[j], make_float4(f0.x, f0.y, f1.x, f1.y));
      }
    }
  }
  #pragma unroll
  for (int j = 0; j < 3; ++j){
    int lx = tid + j*256;
    if (lx < TW) CS4[((size_t)b*NCH + ch)*Wn + x0 + lx] = acc[j];
  }
}

// vAf fused with tk3 (sequential demux — round-15 proven)
__global__ __launch_bounds__(256) void vAf_tk3_kernel(const uint2* __restrict__ F, const float4* __restrict__ CS,
    u32* __restrict__ AB, const float* __restrict__ depth, const u32* __restrict__ selP1, u32* __restrict__ hist2){
  if ((int)blockIdx.x < NVF){
    // ---------------- vAf ----------------
    int gt = blockIdx.x*256 + threadIdx.x;
    int x  = gt % Wn;
    int t2 = gt / Wn;
    int b = t2 % Bn, s = t2 / Bn;
    const uint2* Fb   = F + (size_t)b*HWs;
    const float4* CSb = CS + (size_t)b*NCH*Wn;
    int y0 = s*SEGV;
    int c0 = 2*s - 5; if (c0 < 0) c0 = 0;
    int c1 = 2*s + 5; if (c1 > NCH) c1 = NCH;
    float4 S = make_float4(0,0,0,0);
    for (int c = c0; c < c1; ++c) S = f4add(S, CSb[(size_t)c*Wn + x]);
    u32* ABb = AB + (size_t)b*HWs;
    #pragma unroll 8
    for (int y = y0; y < y0 + SEGV; ++y){
      int ya = y + Rr;
      if (ya < Hn){
        uint2 u = Fb[(size_t)ya*Wn + x];
        float2 f0 = __half22float2(u32_to_h2(u.x)), f1 = __half22float2(u32_to_h2(u.y));
        S.x += f0.x; S.y += f0.y; S.z += f1.x; S.w += f1.y;
      }
      float mI = S.x*NNinv, mp = S.y*NNinv, mIp = S.z*NNinv, mII = S.w*NNinv;
      float var = mII - mI*mI;
      float a  = (mIp - mI*mp) / (var + 1e-3f);
      float bb = mp - a*mI;
      ABb[(size_t)y*Wn + x] = h2_to_u32(__float22half2_rn(make_float2(a, bb)));
      int yb = y - Rr;
      if (yb >= 0){
        uint2 u = Fb[(size_t)yb*Wn + x];
        float2 f0 = __half22float2(u32_to_h2(u.x)), f1 = __half22float2(u32_to_h2(u.y));
        S.x -= f0.x; S.y -= f0.y; S.z -= f1.x; S.w -= f1.y;
      }
    }
  } else {
    // ---------------- tk3 ----------------
    int blk = blockIdx.x - NVF;      // [0, Bn*TK_BPI)
    int idx = blk*2048 + threadIdx.x;
    int b = blk / TK_BPI;
    u32 p1 = selP1[b];
    for (int it = 0; it < 8; ++it, idx += 256){
      u32 u = __float_as_uint(depth[idx]);
      if ((u>>20) == p1) atomicAdd(&hist2[b*65536 + ((u>>4)&0xFFFFu)], 1u);
    }
  }
}

// gB fused with tk5 (sequential demux — round-15 proven)
__global__ __launch_bounds__(256) void gB_tk5_kernel(const u32* __restrict__ AB1, u32* __restrict__ AB2,
    float2* __restrict__ CS2, const float* __restrict__ depth, const float* __restrict__ img,
    const u32* __restrict__ selTau, u32* __restrict__ eqCount, u32* __restrict__ eqVal, u32* __restrict__ eqIdx,
    float* __restrict__ partial){
  __shared__ union SM {
    struct { float2 lds[769]; float2 wtot[4]; } g;
    float wsum[12];
  } sm;
  int tid = threadIdx.x;
  if ((int)blockIdx.x < NGA){
    // ---------------- gB ----------------
    int blk = blockIdx.x;
    int xt = blk & 1;
    int t2 = blk >> 1;
    int b = t2 / NCH, ch = t2 % NCH;
    int x0 = xt*TW;
    int cstart = xt ? (TW - Rr) : 0;
    int lane = tid & 63, wv = tid >> 6;
    float2 acc[3];
    #pragma unroll
    for (int j = 0; j < 3; ++j) acc[j] = make_float2(0,0);
    const u32* rowB = AB1 + (size_t)b*HWs + (size_t)(ch*8)*Wn + cstart;
    u32 pv[3];
    #pragma unroll
    for (int j = 0; j < 3; ++j){
      int i = tid + j*256;
      if (i < CW) pv[j] = rowB[i];
    }
    for (int r = 0; r < 8; ++r){
      int y = ch*8 + r;
      __syncthreads();
      #pragma unroll
      for (int j = 0; j < 3; ++j){
        int i = tid + j*256;
        float2 f = make_float2(0,0);
        if (i < CW) f = __half22float2(u32_to_h2(pv[j]));
        sm.g.lds[i] = f;
      }
      if (r < 7){
        size_t off = (size_t)(r+1)*Wn;
        #pragma unroll
        for (int j = 0; j < 3; ++j){
          int i = tid + j*256;
          if (i < CW) pv[j] = rowB[off+i];
        }
      }
      __syncthreads();
      int base = tid*3;
      float2 loc[3]; float2 tsum = make_float2(0,0);
      #pragma unroll
      for (int j = 0; j < 3; ++j){ loc[j] = sm.g.lds[base+j]; tsum.x += loc[j].x; tsum.y += loc[j].y; }
      float2 v = tsum;
      for (int d = 1; d < 64; d <<= 1){
        float2 o; o.x = __shfl_up(v.x, d); o.y = __shfl_up(v.y, d);
        if (lane >= d){ v.x += o.x; v.y += o.y; }
      }
      if (lane == 63) sm.g.wtot[wv] = v;
      __syncthreads();
      float2 ex = make_float2(v.x - tsum.x, v.y - tsum.y);
      for (int w = 0; w < wv; ++w){ ex.x += sm.g.wtot[w].x; ex.y += sm.g.wtot[w].y; }
      float2 run = ex;
      #pragma unroll
      for (int j = 0; j < 3; ++j){ sm.g.lds[base+j] = run; run.x += loc[j].x; run.y += loc[j].y; }
      __syncthreads();
      #pragma unroll
      for (int j = 0; j < 3; ++j){
        int lx = tid + j*256;
        if (lx < TW){
          int gx = x0 + lx;
          int hi = gx + Rr + 1; if (hi > Wn) hi = Wn;
          int lo = gx - Rr;     if (lo < 0)  lo = 0;
          float2 s = make_float2(sm.g.lds[hi - cstart].x - sm.g.lds[lo - cstart].x,
                                 sm.g.lds[hi - cstart].y - sm.g.lds[lo - cstart].y);
          __half2 h = __float22half2_rn(s);
          AB2[(size_t)b*HWs + (size_t)y*Wn + gx] = h2_to_u32(h);
          float2 fr = __half22float2(h);
          acc[j].x += fr.x; acc[j].y += fr.y;
        }
      }
    }
    #pragma unroll
    for (int j = 0; j < 3; ++j){
      int lx = tid + j*256;
      if (lx < TW) CS2[((size_t)b*NCH + ch)*Wn + x0 + lx] = acc[j];
    }
  } else {
    // ---------------- tk5 ----------------
    int blk = blockIdx.x - NGA;      // [0, Bn*TK_BPI)
    int b = blk / TK_BPI;
    u32 tau = selTau[b];
    int idx = blk*2048 + tid;
    float cr = 0.f, cg = 0.f, cb = 0.f;
    for (int it = 0; it < 8; ++it, idx += 256){
      int pix = idx - b*HWs;
      u32 u = __float_as_uint(depth[idx]);
      u32 u28 = u >> 4;
      if (u28 > tau){
        cr += img[(size_t)(b*3+0)*HWs + pix];
        cg += img[(size_t)(b*3+1)*HWs + pix];
        cb += img[(size_t)(b*3+2)*HWs + pix];
      } else if (u28 == tau){
        u32 p = atomicAdd(&eqCount[b], 1u);
        if (p < EQCAP){ eqVal[b*EQCAP+p] = u; eqIdx[b*EQCAP+p] = (u32)pix; }
      }
    }
    for (int d = 32; d; d >>= 1){
      cr += __shfl_down(cr, d); cg += __shfl_down(cg, d); cb += __shfl_down(cb, d);
    }
    int lane = tid & 63, wv = tid >> 6;
    if (lane == 0){ sm.wsum[wv*3+0] = cr; sm.wsum[wv*3+1] = cg; sm.wsum[wv*3+2] = cb; }
    __syncthreads();
    if (tid == 0){
      float r = 0.f, g = 0.f, bl = 0.f;
      for (int w = 0; w < 4; ++w){ r += sm.wsum[w*3+0]; g += sm.wsum[w*3+1]; bl += sm.wsum[w*3+2]; }
      partial[blk*3+0] = r; partial[blk*3+1] = g; partial[blk*3+2] = bl;
    }
  }
}

// vB: vertical sliding box on (a,b) + fused blend -> out
__global__ __launch_bounds__(256) void vBf_kernel(const u32* __restrict__ AB2, const float2* __restrict__ CS,
    const float* __restrict__ img, const float* __restrict__ Avec, float* __restrict__ out){
  int gt = blockIdx.x*256 + threadIdx.x;
  int x  = gt % Wn;
  int t2 = gt / Wn;
  int b = t2 % Bn, s = t2 / Bn;
  const u32* ABb = AB2 + (size_t)b*HWs;
  const float2* CSb = CS + (size_t)b*NCH*Wn;
  int y0 = s*SEGV;
  int c0 = 2*s - 5; if (c0 < 0) c0 = 0;
  int c1 = 2*s + 5; if (c1 > NCH) c1 = NCH;
  float2 S = make_float2(0,0);
  for (int c = c0; c < c1; ++c){ float2 t = CSb[(size_t)c*Wn + x]; S.x += t.x; S.y += t.y; }
  float A0 = Avec[b*3+0], A1 = Avec[b*3+1], A2 = Avec[b*3+2];
  const float* ir = img + (size_t)(b*3+0)*HWs;
  const float* ig = img + (size_t)(b*3+1)*HWs;
  const float* ib = img + (size_t)(b*3+2)*HWs;
  float* o0 = out + (size_t)(b*3+0)*HWs;
  float* o1 = out + (size_t)(b*3+1)*HWs;
  float* o2 = out + (size_t)(b*3+2)*HWs;
  #pragma unroll 8
  for (int y = y0; y < y0 + SEGV; ++y){
    int ya = y + Rr;
    if (ya < Hn){ float2 t = __half22float2(u32_to_h2(ABb[(size_t)ya*Wn + x])); S.x += t.x; S.y += t.y; }
    float ma = S.x*NNinv, mb = S.y*NNinv;
    size_t idx = (size_t)y*Wn + x;
    float r = ir[idx], g = ig[idx], bb = ib[idx];
    float gray = 0.299f*r + 0.587f*g + 0.114f*bb;
    float t = ma*gray + mb;
    o0[idx] = r *t + A0*(1.0f - t);
    o1[idx] = g *t + A1*(1.0f - t);
    o2[idx] = bb*t + A2*(1.0f - t);
    int yb = y - Rr;
    if (yb >= 0){ float2 t2v = __half22float2(u32_to_h2(ABb[(size_t)yb*Wn + x])); S.x -= t2v.x; S.y -= t2v.y; }
  }
}

// ================= top-k standalone kernels =================

__global__ __launch_bounds__(1024) void tk1_kernel(const float* __restrict__ depth, u32* __restrict__ hist1){
  __shared__ u32 lh[TK1_WAVES*2048];
  int tid = threadIdx.x;
  for (int i = tid; i < TK1_WAVES*2048; i += 1024) lh[i] = 0;
  __syncthreads();
  int b = blockIdx.x >> 5;
  int slice = blockIdx.x & 31;
  const int per = HWs/32;
  int start = b*HWs + slice*per;
  u32* h = &lh[(tid >> 6) * 2048];
  const float2* dp = (const float2*)(depth + start);
  for (int i = tid; i < per/2; i += 1024){
    float2 v = dp[i];
    u32 u0 = __float_as_uint(v.x), u1 = __float_as_uint(v.y);
    u32 b0 = u0 >> 20, b1 = u1 >> 20;
    atomicAdd(&h[b0 >> 1], (b0 & 1u) ? 65536u : 1u);
    atomicAdd(&h[b1 >> 1], (b1 & 1u) ? 65536u : 1u);
  }
  __syncthreads();
  for (int i = tid; i < 4096; i += 1024){
    u32 s = 0;
    for (int w = 0; w < TK1_WAVES; ++w) s += (lh[w*2048 + (i>>1)] >> ((i&1)*16)) & 0xFFFFu;
    if (s) atomicAdd(&hist1[b*4096+i], s);
  }
}

__global__ __launch_bounds__(256) void tk2_kernel(const u32* __restrict__ hist1,
    u32* __restrict__ selP1, u32* __restrict__ selK1){
  int b = blockIdx.x, tid = threadIdx.x;
  const u32* h = hist1 + b*4096;
  u32 cs = 0; int bb = tid*16;
  for (int i = 0; i < 16; ++i) cs += h[bb+i];
  __shared__ u32 sums[256];
  sums[tid] = cs; __syncthreads();
  u32 above = 0;
  for (int t = tid+1; t < 256; ++t) above += sums[t];
  if (above < KTOP && above + cs >= KTOP){
    u32 acc = above;
    for (int i = 15; i >= 0; --i){
      u32 c = h[bb+i]; acc += c;
      if (acc >= KTOP){ selP1[b] = (u32)(bb+i); selK1[b] = KTOP - (acc - c); break; }
    }
  }
}

__global__ __launch_bounds__(256) void tk4_kernel(const u32* __restrict__ hist2, const u32* __restrict__ selP1,
    const u32* __restrict__ selK1, u32* __restrict__ selTau, u32* __restrict__ selK2){
  int b = blockIdx.x, tid = threadIdx.x;
  const u32* h = hist2 + b*65536;
  u32 kk = selK1[b];
  u32 cs = 0; int bb = tid*256;
  for (int i = 0; i < 256; ++i) cs += h[bb+i];
  __shared__ u32 sums[256];
  sums[tid] = cs; __syncthreads();
  u32 above = 0;
  for (int t = tid+1; t < 256; ++t) above += sums[t];
  if (above < kk && above + cs >= kk){
    u32 acc = above;
    for (int i = 255; i >= 0; --i){
      u32 c = h[bb+i]; acc += c;
      if (acc >= kk){ selTau[b] = (selP1[b]<<16) | (u32)(bb+i); selK2[b] = kk - (acc - c); break; }
    }
  }
}

__global__ void tk6_kernel(const float* __restrict__ img, const u32* __restrict__ eqCount,
    u32* __restrict__ eqVal, const u32* __restrict__ eqIdx, const u32* __restrict__ selK2,
    const float* __restrict__ partial, float* __restrict__ Avec){
  int b = blockIdx.x;
  int tid = threadIdx.x;
  float r = 0.f, g = 0.f, bl = 0.f;
  for (int i = tid; i < TK_BPI; i += 64){
    r  += partial[(b*TK_BPI+i)*3+0];
    g  += partial[(b*TK_BPI+i)*3+1];
    bl += partial[(b*TK_BPI+i)*3+2];
  }
  for (int d = 32; d; d >>= 1){
    r += __shfl_down(r, d); g += __shfl_down(g, d); bl += __shfl_down(bl, d);
  }
  if (tid != 0) return;
  u32 m = eqCount[b]; if (m > EQCAP) m = EQCAP;
  u32 need = selK2[b]; if (need > m) need = m;
  float cr = r, cg = g, cb = bl;
  for (u32 it = 0; it < need; ++it){
    int best = -1; u32 bv = 0, bi = 0;
    for (u32 j = 0; j < m; ++j){
      u32 vv = eqVal[b*EQCAP+j];
      if (vv == 0xFFFFFFFFu) continue;
      u32 ix = eqIdx[b*EQCAP+j];
      if (best < 0 || vv > bv || (vv == bv && ix < bi)){ best = (int)j; bv = vv; bi = ix; }
    }
    eqVal[b*EQCAP+best] = 0xFFFFFFFFu;
    cr += img[(size_t)(b*3+0)*HWs + bi];
    cg += img[(size_t)(b*3+1)*HWs + bi];
    cb += img[(size_t)(b*3+2)*HWs + bi];
  }
  float inv = 1.0f/(float)KTOP;
  Avec[b*3+0] = cr*inv; Avec[b*3+1] = cg*inv; Avec[b*3+2] = cb*inv;
}

// ================= FALLBACK (two-half fp32) PATH + standalone tk3/tk5 =================

__global__ __launch_bounds__(256) void tk3_kernel(const float* __restrict__ depth,
    const u32* __restrict__ selP1, u32* __restrict__ hist2){
  int idx = blockIdx.x*2048 + threadIdx.x;
  int b = blockIdx.x / TK_BPI;
  u32 p1 = selP1[b];
  for (int it = 0; it < 8; ++it, idx += 256){
    u32 u = __float_as_uint(depth[idx]);
    if ((u>>20) == p1) atomicAdd(&hist2[b*65536 + ((u>>4)&0xFFFFu)], 1u);
  }
}

__global__ __launch_bounds__(256) void tk5_kernel(const float* __restrict__ depth, const float* __restrict__ img,
    const u32* __restrict__ selTau, u32* __restrict__ eqCount, u32* __restrict__ eqVal, u32* __restrict__ eqIdx,
    float* __restrict__ partial){
  int blk = blockIdx.x;
  int b = blk / TK_BPI;
  u32 tau = selTau[b];
  int idx = blk*2048 + threadIdx.x;
  float cr = 0.f, cg = 0.f, cb = 0.f;
  for (int it = 0; it < 8; ++it, idx += 256){
    int pix = idx - b*HWs;
    u32 u = __float_as_uint(depth[idx]);
    u32 u28 = u >> 4;
    if (u28 > tau){
      cr += img[(size_t)(b*3+0)*HWs + pix];
      cg += img[(size_t)(b*3+1)*HWs + pix];
      cb += img[(size_t)(b*3+2)*HWs + pix];
    } else if (u28 == tau){
      u32 p = atomicAdd(&eqCount[b], 1u);
      if (p < EQCAP){ eqVal[b*EQCAP+p] = u; eqIdx[b*EQCAP+p] = (u32)pix; }
    }
  }
  for (int d = 32; d; d >>= 1){
    cr += __shfl_down(cr, d); cg += __shfl_down(cg, d); cb += __shfl_down(cb, d);
  }
  __shared__ float wsum[4][3];
  int lane = threadIdx.x & 63, wv = threadIdx.x >> 6;
  if (lane == 0){ wsum[wv][0] = cr; wsum[wv][1] = cg; wsum[wv][2] = cb; }
  __syncthreads();
  if (threadIdx.x == 0){
    float r = 0.f, g = 0.f, bl = 0.f;
    for (int w = 0; w < 4; ++w){ r += wsum[w][0]; g += wsum[w][1]; bl += wsum[w][2]; }
    partial[blk*3+0] = r; partial[blk*3+1] = g; partial[blk*3+2] = bl;
  }
}

__global__ __launch_bounds__(256) void hA_kernel(const float* __restrict__ img, const float* __restrict__ depth,
    float4* __restrict__ Fd, float4* __restrict__ Fw, int half){
  __shared__ float4 lds[Wn+1];
  __shared__ float4 wtot[4];
  int blk = blockIdx.x;
  int bl = blk / Hn, y = blk % Hn;
  int b = half*HIMG + bl;
  const float* ir = img + ((size_t)(b*3+0)*Hn + y)*Wn;
  const float* ig = img + ((size_t)(b*3+1)*Hn + y)*Wn;
  const float* ib = img + ((size_t)(b*3+2)*Hn + y)*Wn;
  const float* dp = depth + ((size_t)b*Hn + y)*Wn;
  int tid = threadIdx.x;
  for (int i = tid; i < Wn; i += 256){
    float r = ir[i], g = ig[i], bb = ib[i];
    float I = 0.299f*r + 0.587f*g + 0.114f*bb;
    float p = expf(-BETA_C*dp[i]);
    p = fminf(fmaxf(p, 0.0f), 1.0f);
    lds[i] = make_float4(I, p, I*p, I*I);
  }
  __syncthreads();
  float4 loc[5]; float4 tsum = make_float4(0,0,0,0);
  for (int j = 0; j < 5; ++j){ loc[j] = lds[tid*5+j]; tsum = f4add(tsum, loc[j]); }
  int lane = tid & 63, wv = tid >> 6;
  float4 v = tsum;
  for (int d = 1; d < 64; d <<= 1){
    float4 o; o.x = __shfl_up(v.x, d); o.y = __shfl_up(v.y, d); o.z = __shfl_up(v.z, d); o.w = __shfl_up(v.w, d);
    if (lane >= d) v = f4add(v, o);
  }
  if (lane == 63) wtot[wv] = v;
  __syncthreads();
  float4 ex = f4sub(v, tsum);
  for (int w = 0; w < wv; ++w) ex = f4add(ex, wtot[w]);
  float4 run = ex;
  for (int j = 0; j < 5; ++j){ lds[tid*5+j] = run; run = f4add(run, loc[j]); }
  if (tid == 255) lds[Wn] = run;
  __syncthreads();
  float4* F = (bl < 3) ? (Fd + (size_t)bl*HWs) : Fw;
  for (int j = 0; j < 5; ++j){
    int xx = tid + j*256;
    int hi = xx + Rr + 1; if (hi > Wn) hi = Wn;
    int lo = xx - Rr;     if (lo < 0)  lo = 0;
    F[(size_t)y*Wn + xx] = f4sub(lds[hi], lds[lo]);
  }
}

__global__ __launch_bounds__(256) void cs4_kernel(const float4* __restrict__ Fd, const float4* __restrict__ Fw,
    float4* __restrict__ CS){
  int gt = blockIdx.x*256 + threadIdx.x;
  int x  = gt % Wn;
  int t2 = gt / Wn;
  int bl = t2 % HIMG, ch = t2 / HIMG;
  const float4* F = (bl < 3) ? (Fd + (size_t)bl*HWs) : Fw;
  const float4* p = F + (size_t)ch*8*Wn + x;
  float4 s = make_float4(0,0,0,0);
  #pragma unroll
  for (int i = 0; i < 8; ++i) s = f4add(s, p[(size_t)i*Wn]);
  CS[((size_t)bl*NCH + ch)*Wn + x] = s;
}

__global__ __launch_bounds__(256) void vA_kernel(const float4* __restrict__ Fd, const float4* __restrict__ Fw,
    const float4* __restrict__ CS, float2* __restrict__ AB){
  int gt = blockIdx.x*256 + threadIdx.x;
  int x  = gt % Wn;
  int t2 = gt / Wn;
  int bl = t2 % HIMG, s = t2 / HIMG;
  const float4* F   = (bl < 3) ? (Fd + (size_t)bl*HWs) : Fw;
  const float4* CSb = CS + (size_t)bl*NCH*Wn;
  int y0 = s*SEGV;
  int c0 = 2*s - 5; if (c0 < 0) c0 = 0;
  int c1 = 2*s + 5; if (c1 > NCH) c1 = NCH;
  float4 S = make_float4(0,0,0,0);
  for (int c = c0; c < c1; ++c) S = f4add(S, CSb[(size_t)c*Wn + x]);
  float2* ABb = AB + (size_t)bl*HWs;
  #pragma unroll 2
  for (int y = y0; y < y0 + SEGV; ++y){
    int ya = y + Rr;
    if (ya < Hn) S = f4add(S, F[(size_t)ya*Wn + x]);
    float mI = S.x*NNinv, mp = S.y*NNinv, mIp = S.z*NNinv, mII = S.w*NNinv;
    float var = mII - mI*mI;
    float a  = (mIp - mI*mp) / (var + 1e-3f);
    float bb = mp - a*mI;
    ABb[(size_t)y*Wn + x] = make_float2(a, bb);
    int yb = y - Rr;
    if (yb >= 0) S = f4sub(S, F[(size_t)yb*Wn + x]);
  }
}

__global__ __launch_bounds__(256) void hB_kernel(float2* __restrict__ AB){
  __shared__ float2 lds[Wn+1];
  __shared__ float2 wtot[4];
  int blk = blockIdx.x;
  int bl = blk / Hn, y = blk % Hn;
  float2* row = AB + ((size_t)bl*Hn + y)*Wn;
  int tid = threadIdx.x;
  for (int i = tid; i < Wn; i += 256) lds[i] = row[i];
  __syncthreads();
  float2 loc[5]; float2 tsum = make_float2(0,0);
  for (int j = 0; j < 5; ++j){ loc[j] = lds[tid*5+j]; tsum.x += loc[j].x; tsum.y += loc[j].y; }
  int lane = tid & 63, wv = tid >> 6;
  float2 v = tsum;
  for (int d = 1; d < 64; d <<= 1){
    float2 o; o.x = __shfl_up(v.x, d); o.y = __shfl_up(v.y, d);
    if (lane >= d){ v.x += o.x; v.y += o.y; }
  }
  if (lane == 63) wtot[wv] = v;
  __syncthreads();
  float2 ex = make_float2(v.x - tsum.x, v.y - tsum.y);
  for (int w = 0; w < wv; ++w){ ex.x += wtot[w].x; ex.y += wtot[w].y; }
  float2 run = ex;
  for (int j = 0; j < 5; ++j){ lds[tid*5+j] = run; run.x += loc[j].x; run.y += loc[j].y; }
  if (tid == 255) lds[Wn] = run;
  __syncthreads();
  for (int j = 0; j < 5; ++j){
    int xx = tid + j*256;
    int hi = xx + Rr + 1; if (hi > Wn) hi = Wn;
    int lo = xx - Rr;     if (lo < 0)  lo = 0;
    row[xx] = make_float2(lds[hi].x - lds[lo].x, lds[hi].y - lds[lo].y);
  }
}

__global__ __launch_bounds__(256) void cs2_kernel(const float2* __restrict__ AB, float2* __restrict__ CS){
  int gt = blockIdx.x*256 + threadIdx.x;
  int x  = gt % Wn;
  int t2 = gt / Wn;
  int bl = t2 % HIMG, ch = t2 / HIMG;
  const float2* p = AB + (size_t)bl*HWs + (size_t)ch*8*Wn + x;
  float2 s = make_float2(0,0);
  #pragma unroll
  for (int i = 0; i < 8; ++i){ s.x += p[(size_t)i*Wn].x; s.y += p[(size_t)i*Wn].y; }
  CS[((size_t)bl*NCH + ch)*Wn + x] = s;
}

__global__ __launch_bounds__(256) void vB_kernel(const float2* __restrict__ AB, const float2* __restrict__ CS,
    const float* __restrict__ img, const float* __restrict__ Avec, float* __restrict__ out, int half){
  int gt = blockIdx.x*256 + threadIdx.x;
  int x  = gt % Wn;
  int t2 = gt / Wn;
  int bl = t2 % HIMG, s = t2 / HIMG;
  int b = half*HIMG + bl;
  const float2* ABb = AB + (size_t)bl*HWs;
  const float2* CSb = CS + (size_t)bl*NCH*Wn;
  int y0 = s*SEGV;
  int c0 = 2*s - 5; if (c0 < 0) c0 = 0;
  int c1 = 2*s + 5; if (c1 > NCH) c1 = NCH;
  float2 S = make_float2(0,0);
  for (int c = c0; c < c1; ++c){ float2 t = CSb[(size_t)c*Wn + x]; S.x += t.x; S.y += t.y; }
  float A0 = Avec[b*3+0], A1 = Avec[b*3+1], A2 = Avec[b*3+2];
  const float* ir = img + (size_t)(b*3+0)*HWs;
  const float* ig = img + (size_t)(b*3+1)*HWs;
  const float* ib = img + (size_t)(b*3+2)*HWs;
  float* o0 = out + (size_t)(b*3+0)*HWs;
  float* o1 = out + (size_t)(b*3+1)*HWs;
  float* o2 = out + (size_t)(b*3+2)*HWs;
  #pragma unroll 2
  for (int y = y0; y < y0 + SEGV; ++y){
    int ya = y + Rr;
    if (ya < Hn){ float2 t = ABb[(size_t)ya*Wn + x]; S.x += t.x; S.y += t.y; }
    float ma = S.x*NNinv, mb = S.y*NNinv;
    size_t idx = (size_t)y*Wn + x;
    float r = ir[idx], g = ig[idx], bb = ib[idx];
    float gray = 0.299f*r + 0.587f*g + 0.114f*bb;
    float t = ma*gray + mb;
    o0[idx] = r *t + A0*(1.0f - t);
    o1[idx] = g *t + A1*(1.0f - t);
    o2[idx] = bb*t + A2*(1.0f - t);
    int yb = y - Rr;
    if (yb >= 0){ float2 t2v = ABb[(size_t)yb*Wn + x]; S.x -= t2v.x; S.y -= t2v.y; }
  }
}

// ================= launch =================

extern "C" void kernel_launch(void* const* d_in, const int* in_sizes, int n_in,
                              void* d_out, int out_size, void* d_ws, size_t ws_size,
                              hipStream_t stream){
  const float* img   = (const float*)d_in[0];
  const float* depth = (const float*)d_in[1];
  float* out = (float*)d_out;
  float* ws  = (float*)d_ws;

  const size_t tailFloats = (size_t)ZERO_U32 + 4*Bn + 2*(size_t)Bn*EQCAP
                          + (size_t)Bn*TK_BPI*3 + Bn*3 + 16;
  const size_t needFull = ((size_t)38*HWs + tailFloats) * sizeof(float);
  bool full = (ws_size >= needFull);

  size_t offTail = full ? (size_t)OFF_TAILf : (size_t)OFFH_TAIL;
  u32* tail    = (u32*)(ws + offTail);
  u32* hist1   = tail;                           // Bn*4096
  u32* hist2   = hist1 + Bn*4096;                // Bn*65536
  u32* eqCount = hist2 + (size_t)Bn*65536;       // Bn   (end of zero region)
  u32* selP1   = eqCount + Bn;
  u32* selK1   = selP1 + Bn;
  u32* selTau  = selK1 + Bn;
  u32* selK2   = selTau + Bn;
  u32* eqVal   = selK2 + Bn;                     // Bn*EQCAP
  u32* eqIdx   = eqVal + (size_t)Bn*EQCAP;       // Bn*EQCAP
  float* partial = (float*)(eqIdx + (size_t)Bn*EQCAP);   // Bn*TK_BPI*3
  float* Avec    = partial + (size_t)Bn*TK_BPI*3;        // Bn*3

  fill0_kernel<<<dim3((ZERO_U4 + 255)/256), dim3(256), 0, stream>>>((uint4*)tail);

  if (full){
    uint2*  F   = (uint2*)(ws + OFF_F);
    u32*    AB1 = (u32*)(ws + OFF_AB1);
    u32*    AB2 = (u32*)(ws + OFF_AB2);
    float4* CS4 = (float4*)(ws + OFF_CS4f);
    float2* CS2 = (float2*)(ws + OFF_CS2f);
    tk1_kernel   <<<dim3(Bn*32),            dim3(1024), 0, stream>>>(depth, hist1);
    gA_kernel    <<<dim3(NGA),              dim3(256), 0, stream>>>(img, depth, F, CS4);
    tk2_kernel   <<<dim3(Bn),               dim3(256), 0, stream>>>(hist1, selP1, selK1);
    vAf_tk3_kernel<<<dim3(NVF + Bn*TK_BPI), dim3(256), 0, stream>>>(F, CS4, AB1, depth, selP1, hist2);
    tk4_kernel   <<<dim3(Bn),               dim3(256), 0, stream>>>(hist2, selP1, selK1, selTau, selK2);
    gB_tk5_kernel<<<dim3(NGA + Bn*TK_BPI),  dim3(256), 0, stream>>>(AB1, AB2, CS2, depth, img, selTau,
                                                                    eqCount, eqVal, eqIdx, partial);
    tk6_kernel   <<<dim3(Bn),               dim3(64),  0, stream>>>(img, eqCount, eqVal, eqIdx, selK2, partial, Avec);
    vBf_kernel   <<<dim3(NVF),              dim3(256), 0, stream>>>(AB2, CS2, img, Avec, out);
  } else {
    // fallback: unfused proven chain
    tk1_kernel<<<dim3(Bn*32), dim3(1024), 0, stream>>>(depth, hist1);
    tk2_kernel<<<dim3(Bn),    dim3(256), 0, stream>>>(hist1, selP1, selK1);
    tk3_kernel<<<dim3(Bn*TK_BPI), dim3(256), 0, stream>>>(depth, selP1, hist2);
    tk4_kernel<<<dim3(Bn),    dim3(256), 0, stream>>>(hist2, selP1, selK1, selTau, selK2);
    tk5_kernel<<<dim3(Bn*TK_BPI), dim3(256), 0, stream>>>(depth, img, selTau, eqCount, eqVal, eqIdx, partial);
    tk6_kernel<<<dim3(Bn),    dim3(64),  0, stream>>>(img, eqCount, eqVal, eqIdx, selK2, partial, Avec);
    float4* Fw  = (float4*)(ws + OFFH_FOVF);
    float2* AB  = (float2*)(ws + OFFH_AB);
    float4* CS4 = (float4*)(ws + OFFH_CS4);
    float2* CS2 = (float2*)(ws + OFFH_CS2);
    for (int half = 0; half < 2; ++half){
      float4* Fd = (float4*)out + (size_t)half*3*HWs;
      hA_kernel <<<dim3(HIMG*Hn),            dim3(256), 0, stream>>>(img, depth, Fd, Fw, half);
      cs4_kernel<<<dim3((HIMG*NCH*Wn)/256),  dim3(256), 0, stream>>>(Fd, Fw, CS4);
      vA_kernel <<<dim3((HIMG*Wn*NSEGV)/256),dim3(256), 0, stream>>>(Fd, Fw, CS4, AB);
      hB_kernel <<<dim3(HIMG*Hn),            dim3(256), 0, stream>>>(AB);
      cs2_kernel<<<dim3((HIMG*NCH*Wn)/256),  dim3(256), 0, stream>>>(AB, CS2);
      vB_kernel <<<dim3((HIMG*Wn*NSEGV)/256),dim3(256), 0, stream>>>(AB, CS2, img, Avec, out, half);
    }
  }
}